// Round 14
// baseline (2550.776 us; speedup 1.0000x reference)
//
#include <hip/hip_runtime.h>

#define HID 64
#define TSTEPS 64
#define NTHREADS 256
#define ROWS_PB 128   // 4 waves x 32 rows (2 row-sets of 16 per wave)

typedef __attribute__((ext_vector_type(8))) short bf16x8;
typedef __attribute__((ext_vector_type(4))) float f32x4;

__device__ __forceinline__ float fast_exp2(float x) { return __builtin_amdgcn_exp2f(x); }
__device__ __forceinline__ float fast_rcp(float x)  { return __builtin_amdgcn_rcpf(x); }
#define LOG2E 1.44269504088896341f
#define TWO_L 2.88539008177792682f   // 2*log2(e)

__device__ __forceinline__ unsigned short f2bf(float f) {   // RNE fp32->bf16
    unsigned u = __float_as_uint(f);
    u = u + 0x7fffu + ((u >> 16) & 1u);
    return (unsigned short)(u >> 16);
}
__device__ __forceinline__ float bfh(unsigned short h) { return __uint_as_float(((unsigned)h) << 16); }
__device__ __forceinline__ unsigned cvt_pk_bf16(float a, float b) {  // low16=bf(a), high16=bf(b)
    unsigned r;
    asm("v_cvt_pk_bf16_f32 %0, %1, %2" : "=v"(r) : "v"(a), "v"(b));
    return r;
}

// k-space permutation pi(p) = {p5, p2, p4, p3, p1, p0}:
// B-frag slot (kc*32+8g+j) holds h-unit 16*(2kc+(j>>2)) + 4g + (j&3), so the
// D-layout activations write hB in place (hB[4u+e] = hn[u][e]).
__device__ __forceinline__ int permk(int p) {
    return (p & 0x23) | ((p & 0x04) << 2) | ((p & 0x18) >> 1);
}

// ---------------- LDS layout (bytes) ----------------
//   [0,     32768)  WA   : 16 tiles x 2 frags (bf16 kc0,kc1) x 64 lanes x 16B
//                   i/f/o tiles pre-scaled by -log2e, g tiles by +2log2e
//   [32768, 36864)  EXT  : 16 tiles x 16 rows x 16B (bias+Wih A-frag, g==0 lanes)
//   [36864, 36880)  ZERO : 16B zeros
//   [36880, 39972)  MOG  : fp32 tables (773 floats), pi-permuted, -L scaled
//   [40960, 57344)  XSEQ : fp16 [t=64][row=128]
// stem overlay: buf [0, 34816) = [128 rows][68] f32 (in-place layers), dead
// before WA/EXT staging. 57344 x 2 blocks = 114688 <= LDS pool.
#define OFF_WA    0
#define OFF_EXT   32768
#define OFF_ZERO  36864
#define OFF_MOGB  36880
#define OFF_XSEQ  40960
#define SMEM_TOTAL 57344

#define M0W 0
#define M2W 64
#define M4W 128
#define M1W 192
#define M1B 256
#define M3W 320
#define M3B 384
#define WPo 448
#define BPo 768

__global__ __launch_bounds__(NTHREADS, 2) void moglstm_dual(
    const float* __restrict__ x,
    const float* __restrict__ W1, const float* __restrict__ B1,
    const float* __restrict__ W2, const float* __restrict__ B2,
    const float* __restrict__ W3, const float* __restrict__ B3,
    const float* __restrict__ W4, const float* __restrict__ B4,
    const float* __restrict__ M0w, const float* __restrict__ M0b,
    const float* __restrict__ M1w, const float* __restrict__ M1b,
    const float* __restrict__ M2w, const float* __restrict__ M2b,
    const float* __restrict__ M3w, const float* __restrict__ M3b,
    const float* __restrict__ M4w, const float* __restrict__ M4b,
    const float* __restrict__ Wih, const float* __restrict__ Bih,
    const float* __restrict__ Whh, const float* __restrict__ Bhh,
    const float* __restrict__ Wp,  const float* __restrict__ Bp,
    float* __restrict__ out)
{
    __shared__ __align__(16) char smem[SMEM_TOTAL];
    bf16x8*   WA     = (bf16x8*)(smem + OFF_WA);
    float*    mogf   = (float*)(smem + OFF_MOGB);
    _Float16* sXseqH = (_Float16*)(smem + OFF_XSEQ);
    float*    buf    = (float*)(smem);

    const int tid = threadIdx.x;
    const long rowbase = (long)blockIdx.x * ROWS_PB;

    // ================= MLP stem: 128 rows, in-place single buffer =================
    for (int i = tid; i < ROWS_PB * 16; i += NTHREADS) {
        int r = i >> 4, c4 = i & 15;
        *(float4*)&buf[r * 68 + c4 * 4] = ((const float4*)x)[(rowbase + r) * 16 + c4];
    }
    __syncthreads();
    {
        const int sr = tid & 127;   // row
        const int sq = tid >> 7;    // half: computes units sq*32..+31 (wave-uniform)
        const float* Ws[4] = {W1, W2, W3, W4};
        const float* Bs[4] = {B1, B2, B3, B4};
        float rin[HID];
        #pragma unroll
        for (int L = 0; L < 4; ++L) {
            // read full row into regs, then barrier, then overwrite in place
            #pragma unroll
            for (int k4 = 0; k4 < 16; ++k4) {
                float4 v = *(const float4*)&buf[sr * 68 + k4 * 4];
                rin[4*k4+0] = v.x; rin[4*k4+1] = v.y; rin[4*k4+2] = v.z; rin[4*k4+3] = v.w;
            }
            __syncthreads();
            const float* W = Ws[L];
            const float* Bb = Bs[L];
            #pragma unroll
            for (int jj4 = 0; jj4 < 8; ++jj4) {
                float o[4];
                #pragma unroll
                for (int e = 0; e < 4; ++e) {
                    int j = sq * 32 + jj4 * 4 + e;
                    float a = Bb[j];
                    const float4* wr = (const float4*)(W + j * 64);  // wave-uniform -> s_load
                    #pragma unroll
                    for (int k4 = 0; k4 < 16; ++k4) {
                        float4 w = wr[k4];
                        a += w.x*rin[4*k4] + w.y*rin[4*k4+1] + w.z*rin[4*k4+2] + w.w*rin[4*k4+3];
                    }
                    o[e] = fmaxf(a, 0.0f);
                }
                *(float4*)&buf[sr * 68 + sq * 32 + jj4 * 4] = make_float4(o[0], o[1], o[2], o[3]);
            }
            __syncthreads();
        }
    }

    // ---- transpose stem output to fp16 XSEQ[t][row] (disjoint region) ----
    for (int i = tid; i < TSTEPS * ROWS_PB; i += NTHREADS) {
        int t = i >> 7, r = i & 127;
        sXseqH[i] = (_Float16)buf[r * 68 + t];
    }
    __syncthreads();   // buf reads done; WA/EXT/ZERO/MOG may overwrite overlay

    // ============ stage Whh bf16 A-frags, pi-permuted cols, exp2-prescaled ============
    for (int i = tid; i < 2048; i += NTHREADS) {
        int ln = i & 63, kc = (i >> 6) & 1, tt = i >> 7;
        int gi = tt >> 2, u = tt & 3;          // gi: 0=i 1=f 2=g 3=o
        int r = ln & 15, g = ln >> 4;
        float scl = (gi == 2) ? TWO_L : -LOG2E;
        const float* src = Whh + (gi * 64 + u * 16 + r) * 64;
        union { bf16x8 v; unsigned short s[8]; } f;
        #pragma unroll
        for (int j = 0; j < 8; ++j)
            f.s[j] = f2bf(scl * src[kc * 32 + 16 * (j >> 2) + 4 * g + (j & 3)]);
        WA[(tt * 2 + kc) * 64 + ln] = f.v;
    }
    // compact ext frag (scaled): A[row r][k0..4] = {wih_hi, wih_hi, wih_lo, gb_hi, gb_lo}
    {
        int tt = tid >> 4, r = tid & 15;
        int gi = tt >> 2;
        float scl = (gi == 2) ? TWO_L : -LOG2E;
        int G = gi * 64 + (tt & 3) * 16 + r;
        float wih = scl * Wih[G];
        float gb  = scl * (Bih[G] + Bhh[G]);
        unsigned short wh = f2bf(wih);
        unsigned short wl = f2bf(wih - bfh(wh));
        unsigned short gh = f2bf(gb);
        unsigned short gl = f2bf(gb - bfh(gh));
        union { bf16x8 v; unsigned u[4]; } f;
        f.u[0] = (unsigned)wh | ((unsigned)wh << 16);
        f.u[1] = (unsigned)wl | ((unsigned)gh << 16);
        f.u[2] = (unsigned)gl;
        f.u[3] = 0u;
        *(bf16x8*)(smem + OFF_EXT + tt * 256 + r * 16) = f.v;
    }
    if (tid < 4) ((float*)(smem + OFF_ZERO))[tid] = 0.0f;
    // mog tables: pi-permuted AND pre-scaled by -log2e
    if (tid < 64) {
        int s = permk(tid);
        mogf[M0W + tid] = -LOG2E * M0w[s];
        mogf[M2W + tid] = -LOG2E * M2w[s];
        mogf[M4W + tid] = -LOG2E * M4w[s];
        mogf[M1W + tid] = -LOG2E * M1w[s];
        mogf[M1B + tid] = -LOG2E * M1b[s];
        mogf[M3W + tid] = -LOG2E * M3w[s];
        mogf[M3B + tid] = -LOG2E * M3b[s];
    }
    for (int i = tid; i < 320; i += NTHREADS)
        mogf[WPo + i] = Wp[(i & ~63) + permk(i & 63)];
    if (tid < 5) mogf[BPo + tid] = Bp[tid];
    __syncthreads();

    // ===================== recurrence: 2 row-sets per wave =====================
    const int lane = tid & 63;
    const int wv   = tid >> 6;       // wave 0..3 -> rows wv*32..+31
    const int g_   = lane >> 4;      // 0..3
    const int n    = lane & 15;
    const int r1 = wv * 32 + n;        // row-set 1
    const int r2 = wv * 32 + 16 + n;   // row-set 2

    const char* extb    = smem + ((g_ == 0) ? (OFF_EXT + n * 16) : OFF_ZERO);
    const int   extstep = (g_ == 0) ? 256 : 0;
    const float m0b_s = -LOG2E * M0b[0];
    const float m2b_s = -LOG2E * M2b[0];
    const float m4b_s = -LOG2E * M4b[0];

    float hB1[16], hB2[16];
    f32x4 cst1[4], cst2[4];
    #pragma unroll
    for (int i = 0; i < 16; ++i) { hB1[i] = 0.0f; hB2[i] = 0.0f; }
    #pragma unroll
    for (int u = 0; u < 4; ++u) {
        cst1[u] = (f32x4){0.0f, 0.0f, 0.0f, 0.0f};
        cst2[u] = (f32x4){0.0f, 0.0f, 0.0f, 0.0f};
    }

// dual-row mog dot: shared table reads, tree-reduced partials
#define MOG_DOT2(MOFF, BIAS)                                                  \
    {                                                                         \
        float4 w0 = *(const float4*)&mogf[(MOFF) + g_ * 8];                   \
        float4 w1 = *(const float4*)&mogf[(MOFF) + g_ * 8 + 4];               \
        float4 w2 = *(const float4*)&mogf[(MOFF) + 32 + g_ * 8];              \
        float4 w3 = *(const float4*)&mogf[(MOFF) + 32 + g_ * 8 + 4];          \
        float pa1 = w0.x*hB1[0] + w0.y*hB1[1] + w0.z*hB1[2] + w0.w*hB1[3]     \
                  + w1.x*hB1[4] + w1.y*hB1[5] + w1.z*hB1[6] + w1.w*hB1[7];    \
        float pb1 = w2.x*hB1[8] + w2.y*hB1[9] + w2.z*hB1[10] + w2.w*hB1[11]   \
                  + w3.x*hB1[12] + w3.y*hB1[13] + w3.z*hB1[14] + w3.w*hB1[15];\
        float pa2 = w0.x*hB2[0] + w0.y*hB2[1] + w0.z*hB2[2] + w0.w*hB2[3]     \
                  + w1.x*hB2[4] + w1.y*hB2[5] + w1.z*hB2[6] + w1.w*hB2[7];    \
        float pb2 = w2.x*hB2[8] + w2.y*hB2[9] + w2.z*hB2[10] + w2.w*hB2[11]   \
                  + w3.x*hB2[12] + w3.y*hB2[13] + w3.z*hB2[14] + w3.w*hB2[15];\
        float p1 = pa1 + pb1, p2 = pa2 + pb2;                                 \
        p1 += __shfl_xor(p1, 16);                                             \
        p2 += __shfl_xor(p2, 16);                                             \
        p1 += __shfl_xor(p1, 32);                                             \
        p2 += __shfl_xor(p2, 32);                                             \
        xt1 *= fast_rcp(0.5f + 0.5f * fast_exp2(p1 + (BIAS)));                \
        xt2 *= fast_rcp(0.5f + 0.5f * fast_exp2(p2 + (BIAS)));                \
    }

#define MOG_SCALE2(WOFF, BOFF)                                                \
    {                                                                         \
        _Pragma("unroll")                                                     \
        for (int kc = 0; kc < 2; ++kc) {                                      \
            _Pragma("unroll")                                                 \
            for (int q = 0; q < 2; ++q) {                                     \
                float4 w4 = *(const float4*)&mogf[(WOFF) + kc*32 + g_*8 + q*4]; \
                float4 b4 = *(const float4*)&mogf[(BOFF) + kc*32 + g_*8 + q*4]; \
                int bse = kc * 8 + q * 4;                                     \
                hB1[bse+0] *= fast_rcp(0.5f + 0.5f * fast_exp2(xt1 * w4.x + b4.x)); \
                hB2[bse+0] *= fast_rcp(0.5f + 0.5f * fast_exp2(xt2 * w4.x + b4.x)); \
                hB1[bse+1] *= fast_rcp(0.5f + 0.5f * fast_exp2(xt1 * w4.y + b4.y)); \
                hB2[bse+1] *= fast_rcp(0.5f + 0.5f * fast_exp2(xt2 * w4.y + b4.y)); \
                hB1[bse+2] *= fast_rcp(0.5f + 0.5f * fast_exp2(xt1 * w4.z + b4.z)); \
                hB2[bse+2] *= fast_rcp(0.5f + 0.5f * fast_exp2(xt2 * w4.z + b4.z)); \
                hB1[bse+3] *= fast_rcp(0.5f + 0.5f * fast_exp2(xt1 * w4.w + b4.w)); \
                hB2[bse+3] *= fast_rcp(0.5f + 0.5f * fast_exp2(xt2 * w4.w + b4.w)); \
            }                                                                 \
        }                                                                     \
    }

// h (fp32) -> split-bf16 B-frags for one row-set
#define MKFRAGS(HB, XT, BHI0, BHI1, BLO0, BLO1, BEXT)                         \
    {                                                                         \
        _Pragma("unroll")                                                     \
        for (int kc = 0; kc < 2; ++kc) {                                      \
            _Pragma("unroll")                                                 \
            for (int jp = 0; jp < 4; ++jp) {                                  \
                float a = HB[kc * 8 + 2 * jp], b = HB[kc * 8 + 2 * jp + 1];   \
                unsigned hi = cvt_pk_bf16(a, b);                              \
                float ah = __uint_as_float(hi << 16);                         \
                float bh = __uint_as_float(hi & 0xffff0000u);                 \
                unsigned lo = cvt_pk_bf16(a - ah, b - bh);                    \
                if (kc == 0) { BHI0.u[jp] = hi; BLO0.u[jp] = lo; }            \
                else         { BHI1.u[jp] = hi; BLO1.u[jp] = lo; }            \
            }                                                                 \
        }                                                                     \
        unsigned xh = cvt_pk_bf16(XT, XT) & 0xffffu;                          \
        float xl = XT - bfh((unsigned short)xh);                              \
        unsigned xlp = cvt_pk_bf16(xl, xl) & 0xffffu;                         \
        BEXT.u[0] = xh | (xlp << 16);                                         \
        BEXT.u[1] = xh | (0x3F80u << 16);                                     \
        BEXT.u[2] = 0x3F80u;                                                  \
        BEXT.u[3] = 0u;                                                       \
    }

// fused activations for one row-set's unit-group u (exp2-prescaled gates)
#define ACT(AI, AF, AG, AO, CST, HB, U)                                       \
    {                                                                         \
        _Pragma("unroll")                                                     \
        for (int e = 0; e < 4; ++e) {                                         \
            float A  = fast_exp2(AI[e]);                                      \
            float Bg = fminf(fast_exp2(AG[e]), 3.0e8f);                       \
            float r  = fast_rcp((1.0f + A) * (1.0f + Bg));                    \
            float p1v = (Bg - 1.0f) * r;                                      \
            float sf = fast_rcp(1.0f + fast_exp2(AF[e]));                     \
            float cc = sf * CST[U][e] + p1v;                                  \
            CST[U][e] = cc;                                                   \
            float Ao = fast_exp2(AO[e]);                                      \
            float Bc = fminf(fast_exp2(TWO_L * cc), 3.0e8f);                  \
            float rc = fast_rcp((1.0f + Ao) * (1.0f + Bc));                   \
            HB[U * 4 + e] = (Bc - 1.0f) * rc;                                 \
        }                                                                     \
    }

    #pragma unroll 1
    for (int t = 0; t < TSTEPS; ++t) {
        float xt1 = (float)sXseqH[t * 128 + r1];
        float xt2 = (float)sXseqH[t * 128 + r2];

        // ---- mogrifier, both rows interleaved ----
        MOG_DOT2(M0W, m0b_s)
        MOG_SCALE2(M1W, M1B)
        MOG_DOT2(M2W, m2b_s)
        MOG_SCALE2(M3W, M3B)
        MOG_DOT2(M4W, m4b_s)

        // ---- B-frags for both row-sets ----
        union uf8 { bf16x8 v; unsigned u[4]; };
        uf8 b1hi0, b1hi1, b1lo0, b1lo1, b1ext;
        uf8 b2hi0, b2hi1, b2lo0, b2lo1, b2ext;
        MKFRAGS(hB1, xt1, b1hi0, b1hi1, b1lo0, b1lo1, b1ext)
        MKFRAGS(hB2, xt2, b2hi0, b2hi1, b2lo0, b2lo1, b2ext)

        // ---- gates: shared A-frags, two B-operands (10 MFMAs per tile-pair) ----
        #pragma unroll
        for (int u = 0; u < 4; ++u) {
            f32x4 a1[4], a2[4];
            #pragma unroll
            for (int gi = 0; gi < 4; ++gi) {
                const int tt = gi * 4 + u;
                bf16x8 whi0 = WA[(tt * 2 + 0) * 64 + lane];
                bf16x8 whi1 = WA[(tt * 2 + 1) * 64 + lane];
                bf16x8 wext = *(const bf16x8*)(extb + tt * extstep);
                f32x4 d1 = {0.0f, 0.0f, 0.0f, 0.0f};
                f32x4 d2 = {0.0f, 0.0f, 0.0f, 0.0f};
                d1 = __builtin_amdgcn_mfma_f32_16x16x32_bf16(wext, b1ext.v, d1, 0, 0, 0);
                d2 = __builtin_amdgcn_mfma_f32_16x16x32_bf16(wext, b2ext.v, d2, 0, 0, 0);
                d1 = __builtin_amdgcn_mfma_f32_16x16x32_bf16(whi0, b1hi0.v, d1, 0, 0, 0);
                d2 = __builtin_amdgcn_mfma_f32_16x16x32_bf16(whi0, b2hi0.v, d2, 0, 0, 0);
                d1 = __builtin_amdgcn_mfma_f32_16x16x32_bf16(whi1, b1hi1.v, d1, 0, 0, 0);
                d2 = __builtin_amdgcn_mfma_f32_16x16x32_bf16(whi1, b2hi1.v, d2, 0, 0, 0);
                d1 = __builtin_amdgcn_mfma_f32_16x16x32_bf16(whi0, b1lo0.v, d1, 0, 0, 0);
                d2 = __builtin_amdgcn_mfma_f32_16x16x32_bf16(whi0, b2lo0.v, d2, 0, 0, 0);
                d1 = __builtin_amdgcn_mfma_f32_16x16x32_bf16(whi1, b1lo1.v, d1, 0, 0, 0);
                d2 = __builtin_amdgcn_mfma_f32_16x16x32_bf16(whi1, b2lo1.v, d2, 0, 0, 0);
                a1[gi] = d1;
                a2[gi] = d2;
            }
            ACT(a1[0], a1[1], a1[2], a1[3], cst1, hB1, u)
            ACT(a2[0], a2[1], a2[2], a2[3], cst2, hB2, u)
        }
    }

    // ===================== projection: out = h @ Wp^T + Bp (both rows) =====================
    #pragma unroll
    for (int p = 0; p < 5; ++p) {
        float ap1 = 0.0f, ap2 = 0.0f;
        #pragma unroll
        for (int kc = 0; kc < 2; ++kc) {
            #pragma unroll
            for (int q = 0; q < 2; ++q) {
                float4 w = *(const float4*)&mogf[WPo + p * 64 + kc * 32 + g_ * 8 + q * 4];
                int bse = kc * 8 + q * 4;
                ap1 += w.x * hB1[bse+0] + w.y * hB1[bse+1] + w.z * hB1[bse+2] + w.w * hB1[bse+3];
                ap2 += w.x * hB2[bse+0] + w.y * hB2[bse+1] + w.z * hB2[bse+2] + w.w * hB2[bse+3];
            }
        }
        ap1 += __shfl_xor(ap1, 16);
        ap2 += __shfl_xor(ap2, 16);
        ap1 += __shfl_xor(ap1, 32);
        ap2 += __shfl_xor(ap2, 32);
        if (g_ == 0) {
            float bp = mogf[BPo + p];
            out[(rowbase + r1) * 5 + p] = ap1 + bp;
            out[(rowbase + r2) * 5 + p] = ap2 + bp;
        }
    }
}

extern "C" void kernel_launch(void* const* d_in, const int* in_sizes, int n_in,
                              void* d_out, int out_size, void* d_ws, size_t ws_size,
                              hipStream_t stream) {
    const float* x   = (const float*)d_in[0];
    const float* W1  = (const float*)d_in[1];
    const float* B1  = (const float*)d_in[2];
    const float* W2  = (const float*)d_in[3];
    const float* B2  = (const float*)d_in[4];
    const float* W3  = (const float*)d_in[5];
    const float* B3  = (const float*)d_in[6];
    const float* W4  = (const float*)d_in[7];
    const float* B4  = (const float*)d_in[8];
    const float* M0w = (const float*)d_in[9];
    const float* M0b = (const float*)d_in[10];
    const float* M1w = (const float*)d_in[11];
    const float* M1b = (const float*)d_in[12];
    const float* M2w = (const float*)d_in[13];
    const float* M2b = (const float*)d_in[14];
    const float* M3w = (const float*)d_in[15];
    const float* M3b = (const float*)d_in[16];
    const float* M4w = (const float*)d_in[17];
    const float* M4b = (const float*)d_in[18];
    const float* Wih = (const float*)d_in[19];
    const float* Bih = (const float*)d_in[20];
    const float* Whh = (const float*)d_in[21];
    const float* Bhh = (const float*)d_in[22];
    const float* Wp  = (const float*)d_in[23];
    const float* Bp  = (const float*)d_in[24];

    int B = in_sizes[0] / HID;          // 262144
    int nblocks = B / ROWS_PB;          // 2048

    hipLaunchKernelGGL(moglstm_dual, dim3(nblocks), dim3(NTHREADS), 0, stream,
                       x, W1, B1, W2, B2, W3, B3, W4, B4,
                       M0w, M0b, M1w, M1b, M2w, M2b, M3w, M3b, M4w, M4b,
                       Wih, Bih, Whh, Bhh, Wp, Bp, (float*)d_out);
}